// Round 11
// baseline (129.316 us; speedup 1.0000x reference)
//
#include <hip/hip_runtime.h>
#include <math.h>

// Problem constants (fixed by reference setup_inputs): pred [32,1,512,512] f32
#define IMG_W 512
#define IMG_H 512
#define HW (IMG_W * IMG_H)      // 262144 = 2^18
#define LOGHW 18
#define NIMG 32
#define NTOT (NIMG * HW)        // 8388608
#define TILE 64
#define TPI 64                  // 8x8 tiles of 64x64 per image
#define NTILE (NIMG * TPI)      // 2048
#define CPI 64                  // stat-chunks per image (4096 px each)
#define NSCHUNK (NIMG * CPI)    // 2048
#define EDGE_N (NTILE * 64)     // 131072 entries per edge direction
#define NPAIR (NIMG * 112)      // 56 vertical + 56 horizontal tile-pairs/img
// NOTE (R6 lesson): NO wide cross-kernel counter handshakes. 2048 acq_rel
// fetch_adds to one address serialize ~27ns each = 56us dead. 32-way is fine.

// ---------------- lock-free min-index union-find ----------------------------
__device__ __forceinline__ void uf_unite(int* L, int a, int b) {
    while (true) {
        // find roots (reads may be stale -> only costs retries, never wrong)
        int p = ((volatile int*)L)[a];
        while (p != a) { a = p; p = ((volatile int*)L)[a]; }
        p = ((volatile int*)L)[b];
        while (p != b) { b = p; p = ((volatile int*)L)[b]; }
        if (a == b) return;
        if (a < b) { int t = a; a = b; b = t; }  // a > b
        int old = atomicMin(&L[a], b);
        if (old == a) return;
        a = old;
    }
}

// ---------------- K1a: streaming BCE + row-mask build -----------------------
// Pure streaming kernel (R10's k_local fused 3 unlike workloads; split to
// measure). 2048 blocks x 256 thr; block = 8 image rows. Scalar coalesced
// pred loads (lane i -> px seg*64+i), fused base BCE with native __logf,
// ballot -> u64 fg-mask per (row, 64-px segment) into a 1 MB mask buffer.
__global__ __launch_bounds__(256) void k_stream(const float* __restrict__ pred,
                                                unsigned long long* __restrict__ maskbuf,
                                                float* __restrict__ partials,
                                                unsigned int* __restrict__ counter) {
    __shared__ float wsum[4];
    int b = blockIdx.x;
    int img = b >> 6;
    int y0 = (b & 63) * 8;
    int tid = threadIdx.x;
    int lane = tid & 63, wave = tid >> 6;             // wave 0..3
    const float* pi = pred + ((size_t)img << LOGHW);
    float acc = 0.0f;
#pragma unroll
    for (int i = 0; i < 16; i++) {                    // 2 rows x 8 segments
        int row = y0 + 2 * wave + (i >> 3);
        int seg = i & 7;
        float p = pi[row * IMG_W + seg * 64 + lane];
        acc += fmaxf(__logf(1.0f - p), -100.0f);      // 1-p exact for p>=0.5
        unsigned long long bal = __ballot(p >= 0.5f);
        if (lane == 0) maskbuf[((size_t)(img << 9) + row) * 8 + seg] = bal;
    }
#pragma unroll
    for (int off = 32; off > 0; off >>= 1)
        acc += __shfl_down(acc, off, 64);
    if (lane == 0) wsum[wave] = acc;
    __syncthreads();
    if (tid == 0)
        partials[b] = wsum[0] + wsum[1] + wsum[2] + wsum[3];
    if (b == 0 && tid == 0) *counter = 0u;            // ws is 0xAA-poisoned
}

// ---------------- K1b: mask-based CCL + edge export (no pred access) --------
// One block (1024 thr, 16 waves) per 64x64 tile; reads only 512 B of masks.
//   pass 1': init lab[start]=start from masks.
//   pass 2: vertical contact-run unites; FAST PATH: the row-y run is freshly
//           self-parented, so resolve b's root and atomicMin(&lab[a], bRoot)
//           directly (bRoot < a always: row y-1 indexes < row y); full unite
//           only if a was already linked by a concurrent wave.
//   pass 3a: run-starts chase to root (path halving + full compress).
//   pass 3b: per px: run-start via clz over register mask, ONE lab read;
//            write global L (int4); export 4 tile-edge label vectors.
__global__ __launch_bounds__(1024) void k_ccl(const unsigned long long* __restrict__ maskbuf,
                                              int* __restrict__ L,
                                              int* __restrict__ edges) {
    __shared__ int lab[TILE * TILE];            // 16 KB (start entries only)
    __shared__ unsigned long long msk[TILE];    // 512 B row fg masks
    int tile = blockIdx.x;
    int img = tile >> 6;
    int t = tile & (TPI - 1);
    int ty = t >> 3, tx = t & 7;
    int baseLocal = (ty * TILE) * IMG_W + tx * TILE;  // image-local origin
    int* Li = L + ((size_t)img << LOGHW);
    int tid = threadIdx.x;
    int lane = tid & 63, wave = tid >> 6;             // wave 0..15

    if (tid < 64)
        msk[tid] = maskbuf[((size_t)(img << 9) + ty * 64 + tid) * 8 + tx];
    __syncthreads();
    unsigned long long maskle = (~0ULL) >> (63 - lane);
    // ---- pass 1': start-entry init from masks ------------------------------
#pragma unroll
    for (int j = 0; j < 4; j++) {
        int row = wave + j * 16;
        unsigned long long m = msk[row];
        unsigned long long st = m & ~(m << 1);
        if ((st >> lane) & 1ULL)
            lab[row * TILE + lane] = row * TILE + lane;
    }
    __syncthreads();
    // ---- pass 2: vertical unites, fast-path min-link -----------------------
#pragma unroll
    for (int j = 0; j < 4; j++) {
        int row = wave + j * 16;
        if (row == 0) continue;                   // wave-uniform
        unsigned long long mc = msk[row], mu = msk[row - 1];
        unsigned long long c = mc & mu;
        unsigned long long cs = c & ~(c << 1);    // contact-run starts
        if ((cs >> lane) & 1ULL) {
            unsigned long long stc = mc & ~(mc << 1);
            unsigned long long stu = mu & ~(mu << 1);
            int a = row * TILE + (63 - __builtin_clzll(stc & maskle));
            int b = (row - 1) * TILE + (63 - __builtin_clzll(stu & maskle));
            // find b's root
            int x = b, p = ((volatile int*)lab)[x];
            while (p != x) { x = p; p = ((volatile int*)lab)[x]; }
            int old = atomicMin(&lab[a], x);      // x < a (earlier row)
            if (old != a && old != x) uf_unite(lab, old, x);
        }
    }
    __syncthreads();
    // ---- pass 3a: run-starts chase to root (halving + full compress) -------
#pragma unroll
    for (int j = 0; j < 4; j++) {
        int row = wave + j * 16;
        unsigned long long m = msk[row];
        unsigned long long st = m & ~(m << 1);
        if ((st >> lane) & 1ULL) {
            int i = row * TILE + lane;
            int x = i, p = lab[x];
            while (p != x) {
                int g = lab[p];
                lab[x] = g;          // halving: benign race, ancestors only
                x = g;
                p = lab[x];
            }
            lab[i] = x;              // full compress for the start entry
        }
    }
    __syncthreads();
    // ---- pass 3b: per-px root via register clz + ONE lab read; write L -----
    {
        int i4 = tid * 4;
        int row = i4 >> 6, lx = i4 & 63;
        unsigned long long m = msk[row];
        unsigned long long st = m & ~(m << 1);
        int4 o;
        int* op = (int*)&o;
#pragma unroll
        for (int k = 0; k < 4; k++) {
            int l = lx + k;
            if (!((m >> l) & 1ULL)) op[k] = -1;
            else {
                unsigned long long pre = st & ((~0ULL) >> (63 - l));
                int s = row * TILE + (63 - __builtin_clzll(pre));
                int r = lab[s];                  // start entries = roots now
                op[k] = baseLocal + (r >> 6) * IMG_W + (r & 63);
            }
        }
        *(int4*)(Li + baseLocal + row * IMG_W + lx) = o;
    }
    // ---- edge export: 4 x 64 labels from masks, coalesced ------------------
    if (tid < 256) {
        int e = tid >> 6;                        // 0=T,1=B,2=L,3=R
        int q = tid & 63;
        int val = -1;
        if (e == 0) {                            // top: (0, q)
            unsigned long long m = msk[0];
            if ((m >> q) & 1ULL) {
                unsigned long long st = m & ~(m << 1);
                int s = 63 - __builtin_clzll(st & ((~0ULL) >> (63 - q)));
                int r = lab[s];
                val = baseLocal + (r >> 6) * IMG_W + (r & 63);
            }
        } else if (e == 1) {                     // bottom: (63, q)
            unsigned long long m = msk[63];
            if ((m >> q) & 1ULL) {
                unsigned long long st = m & ~(m << 1);
                int s = 63 * TILE + (63 - __builtin_clzll(st & ((~0ULL) >> (63 - q))));
                int r = lab[s];
                val = baseLocal + (r >> 6) * IMG_W + (r & 63);
            }
        } else if (e == 2) {                     // left: (q, 0) — bit0 is a start
            unsigned long long m = msk[q];
            if (m & 1ULL) {
                int r = lab[q * TILE];
                val = baseLocal + (r >> 6) * IMG_W + (r & 63);
            }
        } else {                                 // right: (q, 63)
            unsigned long long m = msk[q];
            if ((m >> 63) & 1ULL) {
                unsigned long long st = m & ~(m << 1);
                int s = q * TILE + (63 - __builtin_clzll(st));
                int r = lab[s];
                val = baseLocal + (r >> 6) * IMG_W + (r & 63);
            }
        }
        edges[e * EDGE_N + tile * 64 + q] = val;
    }
}

// ---------------- K2: cross-tile border unites from compact edges -----------
__global__ __launch_bounds__(256) void k_border(const int* __restrict__ edges,
                                                int* __restrict__ L) {
    int gid = blockIdx.x * blockDim.x + threadIdx.x;
    int pair = gid >> 6;                 // wave-uniform
    int lane = gid & 63;
    int a, b, img;
    if (pair < NIMG * 56) {              // vertical: (ty,tx)-(ty,tx+1)
        img = pair / 56;
        int w = pair - img * 56;
        int ty = w / 7, tx = w - ty * 7;
        int tl = img * TPI + ty * 8 + tx;
        a = edges[3 * EDGE_N + tl * 64 + lane];        // right edge of left
        b = edges[2 * EDGE_N + (tl + 1) * 64 + lane];  // left edge of right
    } else {                             // horizontal: (ty,tx)-(ty+1,tx)
        int p2 = pair - NIMG * 56;
        img = p2 / 56;
        int w = p2 - img * 56;
        int ty = w >> 3, tx = w & 7;
        int tu = img * TPI + ty * 8 + tx;
        a = edges[1 * EDGE_N + tu * 64 + lane];        // bottom edge of upper
        b = edges[0 * EDGE_N + (tu + 8) * 64 + lane];  // top edge of lower
    }
    bool c = (a >= 0) && (b >= 0);
    unsigned long long cb = __ballot(c);
    unsigned long long cs = cb & ~(cb << 1);           // contact-run starts
    if ((cs >> lane) & 1ULL)
        uf_unite(L + ((size_t)img << LOGHW), a, b);
}

// ---------------- K3: per-chunk stats (4096 px): roots, maxRoot, minFg ------
// Root flags (L[i]==i) are invariant under path compression: no chase needed.
__global__ __launch_bounds__(256) void k_stats(const int* __restrict__ L,
                                               int* __restrict__ cntArr,
                                               int* __restrict__ maxArr,
                                               int* __restrict__ minArr) {
    __shared__ int s1[256], s2[256], s3[256];
    int chunk = blockIdx.x;
    int img = chunk >> 6;
    int baseL = (chunk & 63) * 4096;             // image-local
    const int* Li = L + ((size_t)img << LOGHW);
    int t = threadIdx.x;
    int cnt = 0, mx = -1, mn = HW;
#pragma unroll
    for (int j = 0; j < 4; j++) {
        int off = baseL + (t + j * 256) * 4;
        int4 l4 = *(const int4*)(Li + off);
        const int* lp = (const int*)&l4;
#pragma unroll
        for (int k = 0; k < 4; k++) {
            int local = off + k;
            int p = lp[k];
            bool root = (p == local);
            cnt += root ? 1 : 0;
            if (root && local > mx) mx = local;
            if (p >= 0 && local >= 1 && local < mn) mn = local;
        }
    }
    s1[t] = cnt; s2[t] = mx; s3[t] = mn;
    __syncthreads();
    for (int s = 128; s > 0; s >>= 1) {
        if (t < s) {
            s1[t] += s1[t + s];
            s2[t] = max(s2[t], s2[t + s]);
            s3[t] = min(s3[t], s3[t + s]);
        }
        __syncthreads();
    }
    if (t == 0) { cntArr[chunk] = s1[0]; maxArr[chunk] = s2[0]; minArr[chunk] = s3[0]; }
}

// ---------------- K4: fused rv + correction + final reduce ------------------
// One block per image. v = argmax(lf[1:]) + 1 equals: index of LAST root
// (if >=1); else (single component rooted at 0) first fg index >=1, or 1 if
// none; else 1. rv = v-th root in raster order if 1<=v<=num, else -2.
// If rv >= 0 (rare), this block scans its image for the correction term
// sum_{root==rv}(logp - log1mp). Last of the 32 blocks (32-way counter, not
// R6's 2048-way) reduces k_stream's 2048 base partials + 32 corrections.
__global__ __launch_bounds__(256) void k_tail(const int* __restrict__ cntArr,
                                              const int* __restrict__ maxArr,
                                              const int* __restrict__ minArr,
                                              const int* __restrict__ L,
                                              const float* __restrict__ pred,
                                              const float* __restrict__ partials,
                                              float* __restrict__ corr,
                                              unsigned int* __restrict__ counter,
                                              float* __restrict__ out) {
    __shared__ int sc[256], sm[256], sn[256];
    __shared__ int sel_chunk, sel_base, result;
    __shared__ float sf[256];
    __shared__ double sd[256];
    __shared__ unsigned int oldc;
    int img = blockIdx.x, t = threadIdx.x;
    const int* Li = L + ((size_t)img << LOGHW);
    int cnt = (t < CPI) ? cntArr[img * CPI + t] : 0;
    sc[t] = cnt;
    sm[t] = (t < CPI) ? maxArr[img * CPI + t] : -1;
    sn[t] = (t < CPI) ? minArr[img * CPI + t] : HW;
    if (t == 0) result = -2;
    __syncthreads();
    for (int off = 1; off < 256; off <<= 1) {    // inclusive scan of counts
        int v2 = (t >= off) ? sc[t - off] : 0;
        __syncthreads();
        sc[t] += v2;
        __syncthreads();
    }
    int num = sc[255];
    int inc = sc[t], exc = inc - cnt;
    for (int s = 128; s > 0; s >>= 1) {
        if (t < s) { sm[t] = max(sm[t], sm[t + s]); sn[t] = min(sn[t], sn[t + s]); }
        __syncthreads();
    }
    int last_root = sm[0], minFg = sn[0];
    int v;
    if (last_root >= 1) v = last_root;
    else if (last_root == 0) v = (minFg < HW) ? minFg : 1;
    else v = 1;
    if (v >= 1 && v <= num) {            // block-uniform branch
        if (exc < v && v <= inc) { sel_chunk = t; sel_base = exc; }
        __syncthreads();
        int c = sel_chunk, base = sel_base;
        int baseL = c * 4096;
        int f[16];
        int sum = 0;
#pragma unroll
        for (int j = 0; j < 4; j++) {
            int off = baseL + t * 16 + j * 4;
            int4 l4 = *(const int4*)(Li + off);
            const int* lp = (const int*)&l4;
#pragma unroll
            for (int k = 0; k < 4; k++) {
                f[j * 4 + k] = (lp[k] == off + k) ? 1 : 0;
                sum += f[j * 4 + k];
            }
        }
        __syncthreads();
        sc[t] = sum;
        __syncthreads();
        for (int off = 1; off < 256; off <<= 1) {
            int v2 = (t >= off) ? sc[t - off] : 0;
            __syncthreads();
            sc[t] += v2;
            __syncthreads();
        }
        int exc2 = sc[t] - sum;
        int need = v - base;
        if (exc2 < need && need <= sc[t]) {
            int run = exc2;
#pragma unroll
            for (int k = 0; k < 16; k++) {
                run += f[k];
                if (run == need) { result = baseL + t * 16 + k; break; }
            }
        }
        __syncthreads();
    } else {
        __syncthreads();
    }
    int rvv = result;
    float blocksum = 0.0f;
    if (rvv >= 0) {                      // rare path: scan whole image
        const float* pi = pred + ((size_t)img << LOGHW);
        float acc = 0.0f;
        for (int it = 0; it < HW / 1024; it++) {
            int off = it * 1024 + t * 4;
            float4 p4 = *(const float4*)(pi + off);
            int4 l4 = *(const int4*)(Li + off);
            const float* pp = (const float*)&p4;
            const int* lp = (const int*)&l4;
#pragma unroll
            for (int k = 0; k < 4; k++) {
                int p = lp[k];
                if (p < 0) continue;
                int x = p, q = Li[x];
                while (q != x) { x = q; q = Li[x]; }
                if (x == rvv) {
                    float pr = pp[k];
                    acc += fmaxf(__logf(pr), -100.0f)
                         - fmaxf(__logf(1.0f - pr), -100.0f);
                }
            }
        }
        sf[t] = acc;
        __syncthreads();
        for (int s = 128; s > 0; s >>= 1) {
            if (t < s) sf[t] += sf[t + s];
            __syncthreads();
        }
        blocksum = sf[0];
    }
    if (t == 0) {
        __hip_atomic_store(&corr[img], blocksum, __ATOMIC_RELAXED,
                           __HIP_MEMORY_SCOPE_AGENT);
        oldc = __hip_atomic_fetch_add(counter, 1u, __ATOMIC_ACQ_REL,
                                      __HIP_MEMORY_SCOPE_AGENT);
    }
    __syncthreads();
    if (oldc != NIMG - 1) return;
    // ---- last of 32 blocks: final reduce -----------------------------------
    double acc = 0.0;
#pragma unroll
    for (int j = 0; j < 8; j++) acc += (double)partials[t + j * 256];
    if (t < NIMG)
        acc += (double)__hip_atomic_load(&corr[t], __ATOMIC_ACQUIRE,
                                         __HIP_MEMORY_SCOPE_AGENT);
    sd[t] = acc;
    __syncthreads();
    for (int s = 128; s > 0; s >>= 1) {
        if (t < s) sd[t] += sd[t + s];
        __syncthreads();
    }
    if (t == 0) out[0] = (float)(-sd[0] / (double)NTOT);
}

extern "C" void kernel_launch(void* const* d_in, const int* in_sizes, int n_in,
                              void* d_out, int out_size, void* d_ws, size_t ws_size,
                              hipStream_t stream) {
    const float* pred = (const float*)d_in[0];
    float* out = (float*)d_out;

    char* ws = (char*)d_ws;
    int* L = (int*)ws;                                        // 33.5 MB
    int* edges = (int*)(ws + (size_t)NTOT * 4);               // 2 MB (4 dirs)
    unsigned long long* maskbuf =
        (unsigned long long*)(edges + 4 * EDGE_N);            // 1 MB
    int* cntArr = (int*)(maskbuf + NIMG * 512 * 8);           // 8 KB
    int* maxArr = cntArr + NSCHUNK;                           // 8 KB
    int* minArr = maxArr + NSCHUNK;                           // 8 KB
    float* partials = (float*)(minArr + NSCHUNK);             // 8 KB
    float* corr = partials + NTILE;                           // 128 B
    unsigned int* counter = (unsigned int*)(corr + NIMG);     // 4 B

    k_stream<<<dim3(NTILE), dim3(256), 0, stream>>>(pred, maskbuf, partials, counter);
    k_ccl<<<dim3(NTILE), dim3(1024), 0, stream>>>(maskbuf, L, edges);
    k_border<<<dim3(NPAIR * 64 / 256), dim3(256), 0, stream>>>(edges, L);
    k_stats<<<dim3(NSCHUNK), dim3(256), 0, stream>>>(L, cntArr, maxArr, minArr);
    k_tail<<<dim3(NIMG), dim3(256), 0, stream>>>(cntArr, maxArr, minArr, L, pred,
                                                 partials, corr, counter, out);
}